// Round 7
// baseline (58.624 us; speedup 1.0000x reference)
//
#include <hip/hip_runtime.h>

#define N_BOXES 4194304
#define BCE_COEFF 0.2f
#define BLOCK 256
#define WAVES 4
#define WCHUNK 128                           // boxes per wave-chunk
#define F4_IN (WCHUNK * 5 / 4)               // 160 float4 per input per chunk
#define F4_TOT (F4_IN * 2)                   // 320 float4 (preds + target)
#define NBLOCKS 1024                         // persistent, 4 blocks/CU by LDS
#define BOXES_PER_WAVE (N_BOXES / NBLOCKS / WAVES)   // 1024
#define ROUNDS (BOXES_PER_WAVE / WCHUNK)             // 8

// Async global->LDS DMA, 16 B/lane; linear dest = wave-uniform base + lane*16.
__device__ __forceinline__ void g2lds16(const float4* g, float4* l) {
    __builtin_amdgcn_global_load_lds(
        (const __attribute__((address_space(1))) void*)g,
        (__attribute__((address_space(3))) void*)l,
        16, 0, 0);
}

__global__ __launch_bounds__(BLOCK) void eiou_main(
        const float* __restrict__ preds,
        const float* __restrict__ target,
        float* __restrict__ slots,
        unsigned* __restrict__ flags,
        float* __restrict__ out) {
    // Wave-private double buffers: 4 waves x 2 bufs x 320 float4 = 40960 B.
    __shared__ float4 sbuf[WAVES][2][F4_TOT];

    const int t    = threadIdx.x;
    const int lane = t & 63;
    const int w    = t >> 6;
    const float4* const p4 = reinterpret_cast<const float4*>(preds);
    const float4* const t4 = reinterpret_cast<const float4*>(target);

    const size_t wbase = (size_t)blockIdx.x * (N_BOXES / NBLOCKS * 5 / 4)
                       + (size_t)w * (BOXES_PER_WAVE * 5 / 4);

    auto stage = [&](int c, int b) {
        const size_t fb = wbase + (size_t)c * F4_IN;
#pragma unroll
        for (int k = 0; k < 5; ++k) {
            const int q = k * 64 + lane;                 // 0..319
            const float4* src = (q < F4_IN) ? (p4 + fb + q)
                                            : (t4 + fb + (q - F4_IN));
            g2lds16(src, &sbuf[w][b][q]);
        }
    };

    stage(0, 0);                     // prologue
    float acc = 0.0f;

    // ---- barrier-free per-wave double-buffered pipeline ----
    for (int c = 0; c < ROUNDS; ++c) {
        const int b = c & 1;
        if (c + 1 < ROUNDS) {
            asm volatile("s_waitcnt lgkmcnt(0)" ::: "memory");  // prior reads retired
            stage(c + 1, b ^ 1);                                // in flight under compute
            asm volatile("s_waitcnt vmcnt(5)" ::: "memory");    // chunk c landed
        } else {
            asm volatile("s_waitcnt vmcnt(0)" ::: "memory");
        }

        const float* __restrict__ s = reinterpret_cast<const float*>(&sbuf[w][b][0]);
#pragma unroll
        for (int j = 0; j < 2; ++j) {
            const int box = lane + j * 64;               // 0..127
            const float* __restrict__ P = s + box * 5;
            const float* __restrict__ T = s + WCHUNK * 5 + box * 5;

            const float x = P[0];
            const float y = T[0];
            const float p0 = __fdividef(1.0f, 1.0f + __expf(-P[1]));
            const float p1 = __fdividef(1.0f, 1.0f + __expf(-P[2]));
            const float p2 = __fdividef(1.0f, 1.0f + __expf(-P[3]));
            const float p3 = __fdividef(1.0f, 1.0f + __expf(-P[4]));
            const float t0 = T[1], t1 = T[2], t2 = T[3], t3 = T[4];

            const float xp1 = fminf(p2, p0), xp2 = fmaxf(p2, p0);
            const float yp1 = fminf(p1, p3), yp2 = fmaxf(p1, p3);

            const float wv = xp2 - xp1;        // == |p2-p0|
            const float h  = yp2 - yp1;        // == |p3-p1|
            const float wt = t2 - t0;
            const float ht = t3 - t1;
            const float pred_area   = wv * h;
            const float target_area = wt * ht;

            const float x1 = fmaxf(xp1, t0), x2 = fminf(xp2, t2);
            const float y1 = fmaxf(yp1, t1), y2 = fminf(yp2, t3);

            float ov = (x2 - x1) * (y2 - y1);
            ov = (ov < 0.0f) ? 0.0f : ov;

            const float x1c = fminf(xp1, t0), x2c = fmaxf(xp2, t2);
            const float y1c = fminf(yp1, t1), y2c = fmaxf(yp2, t3);

            const float cw = x2c - x1c, ch = y2c - y1c;

            const float iou = __fdividef(ov, target_area + pred_area - ov);

            const float dx = 0.5f * ((xp1 + xp2) - (t0 + t2));
            const float dy = 0.5f * ((yp1 + yp2) - (t1 + t3));
            const float diag = cw * cw + ch * ch;
            const float center_part = __fdividef(dx * dx + dy * dy, diag);

            // width_part + height_part with a single reciprocal:
            // (dwv/cw)^2 + (dhv/ht)^2 = ((dwv*ht)^2 + (dhv*cw)^2) / (cw*ht)^2
            const float dwv = wv - wt, dhv = h - ht;
            const float a = dwv * ht, bb = dhv * cw, d = cw * ht;
            const float wh_part = __fdividef(a * a + bb * bb, d * d);

            const float eiou = 1.0f - (iou - (center_part + wh_part));

            const float bce = fmaxf(x, 0.0f) - x * y
                            + __logf(1.0f + __expf(-fabsf(x)));

            acc += BCE_COEFF * bce + eiou;
        }
    }

    // ---- block reduction ----
#pragma unroll
    for (int off = 32; off > 0; off >>= 1)
        acc += __shfl_down(acc, off);

    __syncthreads();                 // all LDS pipeline reads done
    float* sf = reinterpret_cast<float*>(&sbuf[0][0][0]);
    if (lane == 0) sf[w] = acc;
    __syncthreads();

    if (t == 0) {
        const float bs = (sf[0] + sf[1]) + (sf[2] + sf[3]);
        // Publish partial: device-scope store, fence, release flag.
        atomicExch(&slots[blockIdx.x], bs);
        __threadfence();
        atomicExch(&flags[blockIdx.x], 1u);   // any prior value (incl. poison) -> 1
    }

    // ---- block 0 gathers all partials (no second dispatch) ----
    if (blockIdx.x == 0) {
        float v = 0.0f;
#pragma unroll
        for (int k = 0; k < NBLOCKS / BLOCK; ++k) {
            const int i = t + k * BLOCK;
            // acquire + self-reset to 0 for the next graph replay
            while (atomicCAS(&flags[i], 1u, 0u) != 1u)
                __builtin_amdgcn_s_sleep(1);
            v += atomicAdd(&slots[i], 0.0f);  // coherent read of the partial
        }
#pragma unroll
        for (int off = 32; off > 0; off >>= 1)
            v += __shfl_down(v, off);

        __syncthreads();
        if (lane == 0) sf[w] = v;
        __syncthreads();
        if (t == 0)
            out[0] = ((sf[0] + sf[1]) + (sf[2] + sf[3])) * (1.0f / (float)N_BOXES);
    }
}

extern "C" void kernel_launch(void* const* d_in, const int* in_sizes, int n_in,
                              void* d_out, int out_size, void* d_ws, size_t ws_size,
                              hipStream_t stream) {
    const float* preds  = (const float*)d_in[0];
    const float* target = (const float*)d_in[1];
    float*    slots = (float*)d_ws;                 // 1024 floats
    unsigned* flags = (unsigned*)((char*)d_ws + NBLOCKS * sizeof(float)); // 1024 u32
    float*    out   = (float*)d_out;

    // Single fused dispatch; flags self-reset each call, poison-tolerant.
    eiou_main<<<NBLOCKS, BLOCK, 0, stream>>>(preds, target, slots, flags, out);
}

// Round 8
// 32.944 us; speedup vs baseline: 1.7795x; 1.7795x over previous
//
#include <hip/hip_runtime.h>

#define N_BOXES 4194304
#define BCE_COEFF 0.2f
#define BLOCK 256
#define WAVES 4
#define WCHUNK 64                            // boxes per wave-chunk (1 box/lane)
#define F4_IN (WCHUNK * 5 / 4)               // 80 float4 per input per chunk
#define F4_TOT (F4_IN * 2)                   // 160 float4 (preds + target)
#define NBLOCKS 2048                         // persistent, exactly 8 blocks/CU
#define BOXES_PER_WAVE (N_BOXES / NBLOCKS / WAVES)   // 512
#define ROUNDS (BOXES_PER_WAVE / WCHUNK)             // 8

// Async global->LDS DMA, 16 B/lane; linear dest = wave-uniform base + lane*16.
__device__ __forceinline__ void g2lds16(const float4* g, float4* l) {
    __builtin_amdgcn_global_load_lds(
        (const __attribute__((address_space(1))) void*)g,
        (__attribute__((address_space(3))) void*)l,
        16, 0, 0);
}

__global__ __launch_bounds__(BLOCK, 8) void eiou_main(
        const float* __restrict__ preds,
        const float* __restrict__ target,
        float* __restrict__ slots) {
    // Wave-private double buffers: 4 waves x 2 bufs x 160 float4 = 20480 B
    // -> exactly 8 blocks/CU (160 KB LDS), 32 waves/CU.
    __shared__ float4 sbuf[WAVES][2][F4_TOT];

    const int t    = threadIdx.x;
    const int lane = t & 63;
    const int w    = t >> 6;
    const float4* const p4 = reinterpret_cast<const float4*>(preds);
    const float4* const t4 = reinterpret_cast<const float4*>(target);

    // Per-input float4 base for this wave: block*2560 + wave*640.
    const size_t wbase = (size_t)blockIdx.x * (N_BOXES / NBLOCKS * 5 / 4)
                       + (size_t)w * (BOXES_PER_WAVE * 5 / 4);

    // Stage one 64-box wave-chunk (2.5 KB): 3 DMA instrs (last half-masked,
    // lanes 0-31 only; mask never all-zero so vmcnt count is always 3).
    auto stage = [&](int c, int b) {
        const size_t fb = wbase + (size_t)c * F4_IN;
#pragma unroll
        for (int k = 0; k < 3; ++k) {
            const int q = k * 64 + lane;                 // 0..191
            if (q < F4_TOT) {
                const float4* src = (q < F4_IN) ? (p4 + fb + q)
                                                : (t4 + fb + (q - F4_IN));
                g2lds16(src, &sbuf[w][b][q]);
            }
        }
    };

    stage(0, 0);                     // prologue
    float acc = 0.0f;

    // ---- barrier-free per-wave double-buffered pipeline ----
    for (int c = 0; c < ROUNDS; ++c) {
        const int b = c & 1;
        if (c + 1 < ROUNDS) {
            asm volatile("s_waitcnt lgkmcnt(0)" ::: "memory");  // prior buf reads retired
            stage(c + 1, b ^ 1);                                // in flight under compute
            asm volatile("s_waitcnt vmcnt(3)" ::: "memory");    // chunk c landed
        } else {
            asm volatile("s_waitcnt vmcnt(0)" ::: "memory");
        }

        const float* __restrict__ s = reinterpret_cast<const float*>(&sbuf[w][b][0]);
        // One box per lane: preds row at s[lane*5], target row at s[320+lane*5].
        const float* __restrict__ P = s + lane * 5;
        const float* __restrict__ T = s + WCHUNK * 5 + lane * 5;

        const float x = P[0];
        const float y = T[0];
        const float p0 = __fdividef(1.0f, 1.0f + __expf(-P[1]));
        const float p1 = __fdividef(1.0f, 1.0f + __expf(-P[2]));
        const float p2 = __fdividef(1.0f, 1.0f + __expf(-P[3]));
        const float p3 = __fdividef(1.0f, 1.0f + __expf(-P[4]));
        const float t0 = T[1], t1 = T[2], t2 = T[3], t3 = T[4];

        const float xp1 = fminf(p2, p0), xp2 = fmaxf(p2, p0);
        const float yp1 = fminf(p1, p3), yp2 = fmaxf(p1, p3);

        const float wv = xp2 - xp1;        // == |p2-p0|
        const float h  = yp2 - yp1;        // == |p3-p1|
        const float wt = t2 - t0;
        const float ht = t3 - t1;
        const float pred_area   = wv * h;
        const float target_area = wt * ht;

        const float x1 = fmaxf(xp1, t0), x2 = fminf(xp2, t2);
        const float y1 = fmaxf(yp1, t1), y2 = fminf(yp2, t3);

        float ov = (x2 - x1) * (y2 - y1);
        ov = (ov < 0.0f) ? 0.0f : ov;

        const float x1c = fminf(xp1, t0), x2c = fmaxf(xp2, t2);
        const float y1c = fminf(yp1, t1), y2c = fmaxf(yp2, t3);

        const float cw = x2c - x1c, ch = y2c - y1c;

        const float iou = __fdividef(ov, target_area + pred_area - ov);

        const float dx = 0.5f * ((xp1 + xp2) - (t0 + t2));
        const float dy = 0.5f * ((yp1 + yp2) - (t1 + t3));
        const float diag = cw * cw + ch * ch;
        const float center_part = __fdividef(dx * dx + dy * dy, diag);

        // width_part + height_part with one reciprocal:
        // (dwv/cw)^2 + (dhv/ht)^2 = ((dwv*ht)^2 + (dhv*cw)^2) / (cw*ht)^2
        const float dwv = wv - wt, dhv = h - ht;
        const float a = dwv * ht, bb = dhv * cw, d = cw * ht;
        const float wh_part = __fdividef(a * a + bb * bb, d * d);

        const float eiou = 1.0f - (iou - (center_part + wh_part));

        const float bce = fmaxf(x, 0.0f) - x * y
                        + __logf(1.0f + __expf(-fabsf(x)));

        acc += BCE_COEFF * bce + eiou;
    }

    // ---- block reduction ----
#pragma unroll
    for (int off = 32; off > 0; off >>= 1)
        acc += __shfl_down(acc, off);

    __syncthreads();                 // all LDS pipeline reads done
    float* sf = reinterpret_cast<float*>(&sbuf[0][0][0]);
    if (lane == 0) sf[w] = acc;
    __syncthreads();
    if (t == 0) slots[blockIdx.x] = (sf[0] + sf[1]) + (sf[2] + sf[3]);
}

__global__ __launch_bounds__(512) void reduce_slots_kernel(
        const float* __restrict__ slots,
        float* __restrict__ out) {
    // 2048 floats = 512 lanes x float4
    const float4 v4 = reinterpret_cast<const float4*>(slots)[threadIdx.x];
    float v = (v4.x + v4.y) + (v4.z + v4.w);
#pragma unroll
    for (int off = 32; off > 0; off >>= 1)
        v += __shfl_down(v, off);

    __shared__ float ws[8];
    const int lane = threadIdx.x & 63;
    const int wid  = threadIdx.x >> 6;
    if (lane == 0) ws[wid] = v;
    __syncthreads();
    if (threadIdx.x == 0) {
        float s = 0.0f;
#pragma unroll
        for (int i = 0; i < 8; ++i) s += ws[i];
        out[0] = s * (1.0f / (float)N_BOXES);
    }
}

extern "C" void kernel_launch(void* const* d_in, const int* in_sizes, int n_in,
                              void* d_out, int out_size, void* d_ws, size_t ws_size,
                              hipStream_t stream) {
    const float* preds  = (const float*)d_in[0];
    const float* target = (const float*)d_in[1];
    float* slots = (float*)d_ws;      // 2048 floats; fully rewritten every call
    float* out   = (float*)d_out;

    eiou_main<<<NBLOCKS, BLOCK, 0, stream>>>(preds, target, slots);
    reduce_slots_kernel<<<1, 512, 0, stream>>>(slots, out);
}